// Round 1
// baseline (302.458 us; speedup 1.0000x reference)
//
#include <hip/hip_runtime.h>

// Problem constants
#define NB 32
#define NS 2048
#define ND 512
#define NFF 512
// scale = 1/sqrt(DFF)
#define SCALE 0.044194173824159216f

__device__ __forceinline__ float dot4(float4 a, float4 b) {
    return a.x * b.x + a.y * b.y + a.z * b.z + a.w * b.w;
}

__device__ __forceinline__ float wave_reduce(float p) {
#pragma unroll
    for (int m = 1; m < 64; m <<= 1) p += __shfl_xor(p, m, 64);
    return p;
}

// ---- K0: swt = sum(Wt) -----------------------------------------------------
__global__ void k_swt(const float* __restrict__ Wt, float* __restrict__ swt) {
    __shared__ float red[256];
    float a = 0.f;
    for (int i = threadIdx.x; i < NS; i += 256) a += Wt[i];
    red[threadIdx.x] = a;
    __syncthreads();
    for (int off = 128; off > 0; off >>= 1) {
        if (threadIdx.x < off) red[threadIdx.x] += red[threadIdx.x + off];
        __syncthreads();
    }
    if (threadIdx.x == 0) *swt = red[0];
}

// ---- K1: xw[b,d] = sum_s Wt[s]*x[b,s,d]   (pass 1 over x) ------------------
// grid = NB*32 blocks (64 rows each), 256 threads
__global__ void __launch_bounds__(256) k_xw(const float* __restrict__ x,
                                            const float* __restrict__ Wt,
                                            float* __restrict__ xw) {
    const int b = blockIdx.x >> 5;
    const int chunk = blockIdx.x & 31;
    const int s0 = chunk * 64;
    const int t = threadIdx.x;
    const int col = t & 127;   // float4 column
    const int half = t >> 7;   // row interleave (0/1)
    const float4* xb = (const float4*)(x + (size_t)b * NS * ND);
    float4 acc = make_float4(0.f, 0.f, 0.f, 0.f);
#pragma unroll 4
    for (int i = 0; i < 32; i++) {
        int s = s0 + half + 2 * i;
        float w = Wt[s];
        float4 v = xb[(size_t)s * 128 + col];
        acc.x += w * v.x; acc.y += w * v.y; acc.z += w * v.z; acc.w += w * v.w;
    }
    __shared__ float4 red[128];
    if (half == 1) red[col] = acc;
    __syncthreads();
    if (half == 0) {
        float4 o = red[col];
        float* dst = xw + b * ND + 4 * col;
        atomicAdd(dst + 0, acc.x + o.x);
        atomicAdd(dst + 1, acc.y + o.y);
        atomicAdd(dst + 2, acc.z + o.z);
        atomicAdd(dst + 3, acc.w + o.w);
    }
}

// ---- K2: kw[b,f] = xw[b,:].Wk[f,:] + bk[f]*swt -----------------------------
// grid = 256 blocks x 256 thr = 1024 waves, one wave -> 16 outputs
__global__ void __launch_bounds__(256) k_kw(const float* __restrict__ xw,
                                            const float* __restrict__ Wk,
                                            const float* __restrict__ bk,
                                            const float* __restrict__ swt,
                                            float* __restrict__ kw) {
    const int gw = blockIdx.x * 4 + (threadIdx.x >> 6);
    const int lane = threadIdx.x & 63;
    const int b = gw >> 5;
    const int f0 = (gw & 31) * 16;
    const float4* xw4 = (const float4*)(xw + b * ND);
    const float4 xa = xw4[lane];
    const float4 xc = xw4[64 + lane];
    const float sw = *swt;
#pragma unroll 4
    for (int j = 0; j < 16; j++) {
        int f = f0 + j;
        const float4* wr = (const float4*)(Wk + (size_t)f * ND);
        float p = dot4(xa, wr[lane]) + dot4(xc, wr[64 + lane]);
        p = wave_reduce(p);
        if (lane == 0) kw[b * NFF + f] = p + bk[f] * sw;
    }
}

// ---- K3: wqs[b,d] = SCALE * sum_f kw[b,f]*Wq[f,d];  cb2[b] = SCALE*kw.bq+bt
// grid = NB blocks, 512 threads (thread = d)
__global__ void __launch_bounds__(512) k_wqkw(const float* __restrict__ kw,
                                              const float* __restrict__ Wq,
                                              const float* __restrict__ bq,
                                              const float* __restrict__ bt,
                                              float* __restrict__ wqs,
                                              float* __restrict__ cb2) {
    const int b = blockIdx.x;
    const int t = threadIdx.x;
    __shared__ float kwl[NFF];
    kwl[t] = kw[b * NFF + t];
    __syncthreads();
    float acc = 0.f;
#pragma unroll 8
    for (int f = 0; f < NFF; f++) acc += kwl[f] * Wq[(size_t)f * ND + t];
    wqs[b * ND + t] = acc * SCALE;
    // cb2 = SCALE * dot(kw, bq) + bt
    __shared__ float red[512];
    red[t] = kwl[t] * bq[t];
    __syncthreads();
    for (int off = 256; off > 0; off >>= 1) {
        if (t < off) red[t] += red[t + off];
        __syncthreads();
    }
    if (t == 0) cb2[b] = red[0] * SCALE + bt[0];
}

// ---- K4: ta[b,s] = x[b,s,:].wqs[b,:] + cb2[b];
//          xt[b,d] += ta*x[b,s,d]; st[b] += ta   (pass 2 over x, fused) ------
// grid = NB*32 blocks (64 rows), 256 threads = 4 waves, 16 rows/wave
__global__ void __launch_bounds__(256) k_ta_xt(const float* __restrict__ x,
                                               const float* __restrict__ wqs,
                                               const float* __restrict__ cb2,
                                               float* __restrict__ xt,
                                               float* __restrict__ st) {
    const int b = blockIdx.x >> 5;
    const int chunk = blockIdx.x & 31;
    const int wave = threadIdx.x >> 6;
    const int lane = threadIdx.x & 63;
    const float4* xb = (const float4*)(x + (size_t)b * NS * ND);
    const float4* wq4 = (const float4*)(wqs + b * ND);
    const float4 w0 = wq4[lane];
    const float4 w1 = wq4[64 + lane];
    const float c = cb2[b];
    float4 a0 = make_float4(0.f, 0.f, 0.f, 0.f);
    float4 a1 = make_float4(0.f, 0.f, 0.f, 0.f);
    float sta = 0.f;
#pragma unroll 2
    for (int i = 0; i < 16; i++) {
        int s = chunk * 64 + wave * 16 + i;
        float4 v0 = xb[(size_t)s * 128 + lane];
        float4 v1 = xb[(size_t)s * 128 + 64 + lane];
        float p = dot4(v0, w0) + dot4(v1, w1);
        p = wave_reduce(p);
        float ta = p + c;
        a0.x += ta * v0.x; a0.y += ta * v0.y; a0.z += ta * v0.z; a0.w += ta * v0.w;
        a1.x += ta * v1.x; a1.y += ta * v1.y; a1.z += ta * v1.z; a1.w += ta * v1.w;
        sta += ta;
    }
    __shared__ float4 sh0[4][128];
    __shared__ float4 sh1[4][128];
    __shared__ float stw[4];
    sh0[wave][lane] = a0;          // lane covers d/4 in [0,64)
    sh0[wave][64 + lane] = a1;     // wait: need distinct slots per half
    // NOTE: a0 owns d=4*lane, a1 owns d=256+4*lane -> store in two arrays
    sh1[wave][lane] = a1;
    if (lane == 0) stw[wave] = sta;
    __syncthreads();
    const int t = threadIdx.x;
    if (t < 64) {
        float4 s0 = sh0[0][t], s1 = sh0[1][t], s2 = sh0[2][t], s3 = sh0[3][t];
        float* dst = xt + b * ND + 4 * t;
        atomicAdd(dst + 0, s0.x + s1.x + s2.x + s3.x);
        atomicAdd(dst + 1, s0.y + s1.y + s2.y + s3.y);
        atomicAdd(dst + 2, s0.z + s1.z + s2.z + s3.z);
        atomicAdd(dst + 3, s0.w + s1.w + s2.w + s3.w);
    } else if (t < 128) {
        int l = t - 64;
        float4 s0 = sh1[0][l], s1 = sh1[1][l], s2 = sh1[2][l], s3 = sh1[3][l];
        float* dst = xt + b * ND + 256 + 4 * l;
        atomicAdd(dst + 0, s0.x + s1.x + s2.x + s3.x);
        atomicAdd(dst + 1, s0.y + s1.y + s2.y + s3.y);
        atomicAdd(dst + 2, s0.z + s1.z + s2.z + s3.z);
        atomicAdd(dst + 3, s0.w + s1.w + s2.w + s3.w);
    } else if (t == 128) {
        atomicAdd(st + b, stw[0] + stw[1] + stw[2] + stw[3]);
    }
}

// ---- K5: out[b,f] = xt[b,:].Wv[f,:] + bv[f]*st[b] --------------------------
__global__ void __launch_bounds__(256) k_latent(const float* __restrict__ xt,
                                                const float* __restrict__ Wv,
                                                const float* __restrict__ bv,
                                                const float* __restrict__ st,
                                                float* __restrict__ out) {
    const int gw = blockIdx.x * 4 + (threadIdx.x >> 6);
    const int lane = threadIdx.x & 63;
    const int b = gw >> 5;
    const int f0 = (gw & 31) * 16;
    const float4* xt4 = (const float4*)(xt + b * ND);
    const float4 xa = xt4[lane];
    const float4 xc = xt4[64 + lane];
    const float stb = st[b];
#pragma unroll 4
    for (int j = 0; j < 16; j++) {
        int f = f0 + j;
        const float4* wr = (const float4*)(Wv + (size_t)f * ND);
        float p = dot4(xa, wr[lane]) + dot4(xc, wr[64 + lane]);
        p = wave_reduce(p);
        if (lane == 0) out[b * NFF + f] = p + bv[f] * stb;
    }
}

extern "C" void kernel_launch(void* const* d_in, const int* in_sizes, int n_in,
                              void* d_out, int out_size, void* d_ws, size_t ws_size,
                              hipStream_t stream) {
    const float* x  = (const float*)d_in[0];
    const float* Wq = (const float*)d_in[1];
    const float* bq = (const float*)d_in[2];
    const float* Wk = (const float*)d_in[3];
    const float* bk = (const float*)d_in[4];
    const float* Wv = (const float*)d_in[5];
    const float* bv = (const float*)d_in[6];
    const float* Wt = (const float*)d_in[7];
    const float* bt = (const float*)d_in[8];
    float* out = (float*)d_out;

    float* w = (float*)d_ws;
    float* xw  = w;                 // 16384 (zeroed)
    float* xt  = w + 16384;         // 16384 (zeroed)
    float* st  = w + 32768;         // 32    (zeroed)
    float* swt = w + 32800;         // 1
    float* kw  = w + 32832;         // 16384
    float* wqs = w + 49216;         // 16384
    float* cb2 = w + 65600;         // 32

    // zero the accumulators (xw, xt, st)
    hipMemsetAsync(d_ws, 0, (size_t)(32768 + 32) * sizeof(float), stream);

    k_swt<<<1, 256, 0, stream>>>(Wt, swt);
    k_xw<<<NB * 32, 256, 0, stream>>>(x, Wt, xw);
    k_kw<<<256, 256, 0, stream>>>(xw, Wk, bk, swt, kw);
    k_wqkw<<<NB, 512, 0, stream>>>(kw, Wq, bq, bt, wqs, cb2);
    k_ta_xt<<<NB * 32, 256, 0, stream>>>(x, wqs, cb2, xt, st);
    k_latent<<<256, 256, 0, stream>>>(xt, Wv, bv, st, out);
}

// Round 2
// 294.984 us; speedup vs baseline: 1.0253x; 1.0253x over previous
//
#include <hip/hip_runtime.h>

// Problem constants
#define NB 32
#define NS 2048
#define ND 512
#define NFF 512
// scale = 1/sqrt(DFF)
#define SCALE 0.044194173824159216f

__device__ __forceinline__ float dot4(float4 a, float4 b) {
    return a.x * b.x + a.y * b.y + a.z * b.z + a.w * b.w;
}

__device__ __forceinline__ float wave_reduce(float p) {
#pragma unroll
    for (int m = 1; m < 64; m <<= 1) p += __shfl_xor(p, m, 64);
    return p;
}

// ---- K1: xwp[b*32+chunk][d] = sum_{s in chunk} Wt[s]*x[b,s,d]  (pass 1) ----
// grid = NB*32 blocks (64 rows each), 256 threads. No atomics: per-block
// partials, reduced by k_kwq.
__global__ void __launch_bounds__(256) k_xw(const float* __restrict__ x,
                                            const float* __restrict__ Wt,
                                            float* __restrict__ xwp) {
    const int b = blockIdx.x >> 5;
    const int chunk = blockIdx.x & 31;
    const int s0 = chunk * 64;
    const int t = threadIdx.x;
    const int col = t & 127;   // float4 column
    const int half = t >> 7;   // row interleave (0/1)
    const float4* xb = (const float4*)(x + (size_t)b * NS * ND);
    float4 acc = make_float4(0.f, 0.f, 0.f, 0.f);
#pragma unroll 4
    for (int i = 0; i < 32; i++) {
        int s = s0 + half + 2 * i;
        float w = Wt[s];
        float4 v = xb[(size_t)s * 128 + col];
        acc.x += w * v.x; acc.y += w * v.y; acc.z += w * v.z; acc.w += w * v.w;
    }
    __shared__ float4 red[128];
    if (half == 1) red[col] = acc;
    __syncthreads();
    if (half == 0) {
        float4 o = red[col];
        o.x += acc.x; o.y += acc.y; o.z += acc.z; o.w += acc.w;
        ((float4*)xwp)[(size_t)blockIdx.x * 128 + col] = o;
    }
}

// ---- K2 (fused): per batch b:
//   xw[d]  = sum_c xwp[b*32+c][d]
//   swt    = sum(Wt)
//   kw[f]  = xw . Wk[f,:] + bk[f]*swt
//   wqs[d] = SCALE * sum_f kw[f]*Wq[f,d]
//   cb2    = SCALE * kw.bq + bt
// grid = NB blocks, 1024 threads (16 waves)
__global__ void __launch_bounds__(1024) k_kwq(const float* __restrict__ xwp,
                                              const float* __restrict__ Wt,
                                              const float* __restrict__ Wk,
                                              const float* __restrict__ bk,
                                              const float* __restrict__ Wq,
                                              const float* __restrict__ bq,
                                              const float* __restrict__ bt,
                                              float* __restrict__ wqs,
                                              float* __restrict__ cb2) {
    const int b = blockIdx.x;
    const int t = threadIdx.x;
    const int wv = t >> 6;
    const int lane = t & 63;
    __shared__ float xw[ND];
    __shared__ float kwl[NFF];
    __shared__ float part[2][ND];
    __shared__ float cbred[16];
    __shared__ float swt_s;

    // Stage A: reduce xwp partials; wave 15 computes swt = sum(Wt)
    if (t < ND) {
        float a = 0.f;
        const float* p = xwp + (size_t)b * 32 * ND + t;
#pragma unroll
        for (int c = 0; c < 32; c++) a += p[c * ND];
        xw[t] = a;
    }
    if (wv == 15) {
        float a = 0.f;
#pragma unroll
        for (int j = 0; j < 32; j++) a += Wt[j * 64 + lane];
        a = wave_reduce(a);
        if (lane == 0) swt_s = a;
    }
    __syncthreads();

    // Stage B: kw[f] for f = wv*32 .. wv*32+31, one f per wave-iteration
    {
        const float4* xw4 = (const float4*)xw;
        const float4 xa = xw4[lane];
        const float4 xc = xw4[64 + lane];
        const float sw = swt_s;
        float cbp = 0.f;
#pragma unroll 4
        for (int j = 0; j < 32; j++) {
            int f = wv * 32 + j;
            const float4* wr = (const float4*)(Wk + (size_t)f * ND);
            float p = dot4(xa, wr[lane]) + dot4(xc, wr[64 + lane]);
            p = wave_reduce(p);
            if (lane == 0) {
                float kf = p + bk[f] * sw;
                kwl[f] = kf;
                cbp += kf * bq[f];
            }
        }
        if (lane == 0) cbred[wv] = cbp;
    }
    __syncthreads();

    // Stage C: wqs[d] = SCALE * sum_f kwl[f]*Wq[f,d]; split f-range over 2 halves
    {
        const int d = t & 511;
        const int h = t >> 9;
        float acc = 0.f;
        const int f0 = h * 256;
#pragma unroll 8
        for (int j = 0; j < 256; j++) {
            int f = f0 + j;
            acc += kwl[f] * Wq[(size_t)f * ND + d];
        }
        part[h][d] = acc;
        if (t == 0) {
            float s = 0.f;
#pragma unroll
            for (int w = 0; w < 16; w++) s += cbred[w];
            cb2[b] = SCALE * s + bt[0];
        }
    }
    __syncthreads();
    if (t < ND) wqs[b * ND + t] = SCALE * (part[0][t] + part[1][t]);
}

// ---- K3: ta[b,s] = x[b,s,:].wqs[b,:] + cb2[b];
//   per-block partials: xtp[b*32+chunk][d] = sum_s ta*x[b,s,d],
//                       stp[b*32+chunk]    = sum_s ta          (pass 2) ------
// grid = NB*32 blocks (64 rows), 256 threads = 4 waves, 16 rows/wave
__global__ void __launch_bounds__(256) k_ta_xt(const float* __restrict__ x,
                                               const float* __restrict__ wqs,
                                               const float* __restrict__ cb2,
                                               float* __restrict__ xtp,
                                               float* __restrict__ stp) {
    const int b = blockIdx.x >> 5;
    const int chunk = blockIdx.x & 31;
    const int wave = threadIdx.x >> 6;
    const int lane = threadIdx.x & 63;
    const float4* xb = (const float4*)(x + (size_t)b * NS * ND);
    const float4* wq4 = (const float4*)(wqs + b * ND);
    const float4 w0 = wq4[lane];
    const float4 w1 = wq4[64 + lane];
    const float c = cb2[b];
    float4 a0 = make_float4(0.f, 0.f, 0.f, 0.f);
    float4 a1 = make_float4(0.f, 0.f, 0.f, 0.f);
    float sta = 0.f;
#pragma unroll 2
    for (int i = 0; i < 16; i++) {
        int s = chunk * 64 + wave * 16 + i;
        float4 v0 = xb[(size_t)s * 128 + lane];
        float4 v1 = xb[(size_t)s * 128 + 64 + lane];
        float p = dot4(v0, w0) + dot4(v1, w1);
        p = wave_reduce(p);
        float ta = p + c;
        a0.x += ta * v0.x; a0.y += ta * v0.y; a0.z += ta * v0.z; a0.w += ta * v0.w;
        a1.x += ta * v1.x; a1.y += ta * v1.y; a1.z += ta * v1.z; a1.w += ta * v1.w;
        sta += ta;
    }
    __shared__ float4 sh0[4][64];   // a0: d = 4*lane       in [0,256)
    __shared__ float4 sh1[4][64];   // a1: d = 256 + 4*lane in [256,512)
    __shared__ float stw[4];
    sh0[wave][lane] = a0;
    sh1[wave][lane] = a1;
    if (lane == 0) stw[wave] = sta;
    __syncthreads();
    const int t = threadIdx.x;
    float4* dst = (float4*)xtp + (size_t)blockIdx.x * 128;
    if (t < 64) {
        float4 s0 = sh0[0][t], s1 = sh0[1][t], s2 = sh0[2][t], s3 = sh0[3][t];
        dst[t] = make_float4(s0.x + s1.x + s2.x + s3.x,
                             s0.y + s1.y + s2.y + s3.y,
                             s0.z + s1.z + s2.z + s3.z,
                             s0.w + s1.w + s2.w + s3.w);
    } else if (t < 128) {
        int l = t - 64;
        float4 s0 = sh1[0][l], s1 = sh1[1][l], s2 = sh1[2][l], s3 = sh1[3][l];
        dst[64 + l] = make_float4(s0.x + s1.x + s2.x + s3.x,
                                  s0.y + s1.y + s2.y + s3.y,
                                  s0.z + s1.z + s2.z + s3.z,
                                  s0.w + s1.w + s2.w + s3.w);
    } else if (t == 128) {
        stp[blockIdx.x] = stw[0] + stw[1] + stw[2] + stw[3];
    }
}

// ---- K4: out[b,f] = xt[b,:].Wv[f,:] + bv[f]*st[b], reducing xtp/stp --------
// grid = 256 blocks (8 per b), 256 threads = 4 waves, 16 f per wave
__global__ void __launch_bounds__(256) k_latent(const float* __restrict__ xtp,
                                                const float* __restrict__ stp,
                                                const float* __restrict__ Wv,
                                                const float* __restrict__ bv,
                                                float* __restrict__ out) {
    const int b = blockIdx.x >> 3;
    const int t = threadIdx.x;
    __shared__ float xt[ND];
    __shared__ float sts;
    {
        float a0 = 0.f, a1 = 0.f;
        const float* p = xtp + (size_t)b * 32 * ND;
#pragma unroll
        for (int c = 0; c < 32; c++) {
            a0 += p[c * ND + t];
            a1 += p[c * ND + 256 + t];
        }
        xt[t] = a0;
        xt[256 + t] = a1;
        if (t == 0) {
            float s = 0.f;
            const float* sp = stp + b * 32;
#pragma unroll
            for (int c = 0; c < 32; c++) s += sp[c];
            sts = s;
        }
    }
    __syncthreads();
    const int wv = t >> 6;
    const int lane = t & 63;
    const int f0 = ((blockIdx.x & 7) * 4 + wv) * 16;
    const float4* xt4 = (const float4*)xt;
    const float4 xa = xt4[lane];
    const float4 xc = xt4[64 + lane];
    const float stb = sts;
#pragma unroll 4
    for (int j = 0; j < 16; j++) {
        int f = f0 + j;
        const float4* wr = (const float4*)(Wv + (size_t)f * ND);
        float p = dot4(xa, wr[lane]) + dot4(xc, wr[64 + lane]);
        p = wave_reduce(p);
        if (lane == 0) out[b * NFF + f] = p + bv[f] * stb;
    }
}

extern "C" void kernel_launch(void* const* d_in, const int* in_sizes, int n_in,
                              void* d_out, int out_size, void* d_ws, size_t ws_size,
                              hipStream_t stream) {
    const float* x  = (const float*)d_in[0];
    const float* Wq = (const float*)d_in[1];
    const float* bq = (const float*)d_in[2];
    const float* Wk = (const float*)d_in[3];
    const float* bk = (const float*)d_in[4];
    const float* Wv = (const float*)d_in[5];
    const float* bv = (const float*)d_in[6];
    const float* Wt = (const float*)d_in[7];
    const float* bt = (const float*)d_in[8];
    float* out = (float*)d_out;

    float* w = (float*)d_ws;
    float* xwp = w;                       // 32*32*512 = 524288
    float* xtp = w + 524288;              // 524288
    float* stp = w + 1048576;             // 1024
    float* wqs = w + 1049600;             // 16384
    float* cb2 = w + 1065984;             // 32

    k_xw<<<NB * 32, 256, 0, stream>>>(x, Wt, xwp);
    k_kwq<<<NB, 1024, 0, stream>>>(xwp, Wt, Wk, bk, Wq, bq, bt, wqs, cb2);
    k_ta_xt<<<NB * 32, 256, 0, stream>>>(x, wqs, cb2, xtp, stp);
    k_latent<<<256, 256, 0, stream>>>(xtp, stp, Wv, bv, out);
}